// Round 6
// baseline (321.948 us; speedup 1.0000x reference)
//
#include <hip/hip_runtime.h>

typedef __bf16 bf16x8 __attribute__((ext_vector_type(8)));
typedef float f32x4 __attribute__((ext_vector_type(4)));

#define T_LEN 200
#define NB 4096

__device__ __forceinline__ f32x4 mfma16(bf16x8 a, bf16x8 b, f32x4 c) {
    return __builtin_amdgcn_mfma_f32_16x16x32_bf16(a, b, c, 0, 0, 0);
}
// raw v_rcp_f32 (1 ulp) transcendentals; saturation exact (rcp(inf)=0)
__device__ __forceinline__ float sigf(float x) {
    return __builtin_amdgcn_rcpf(1.0f + __expf(-x));
}
__device__ __forceinline__ float tanh_fast(float x) {
    return 1.0f - 2.0f * __builtin_amdgcn_rcpf(__expf(2.0f * x) + 1.0f);
}
__device__ __forceinline__ unsigned packRNE2(float a, float b) {
    unsigned ha = (unsigned)__builtin_bit_cast(unsigned short, (__bf16)a);
    unsigned hb = (unsigned)__builtin_bit_cast(unsigned short, (__bf16)b);
    return ha | (hb << 16);
}
__device__ __forceinline__ void publish_hi(unsigned short* hp, float v) {
    __bf16 h = (__bf16)v;
    *hp = __builtin_bit_cast(unsigned short, h);
}
struct Frag { bf16x8 hi, lo; };
__device__ __forceinline__ Frag make_frag(f32x4 a, f32x4 b) {
    Frag f;
    #pragma unroll
    for (int j = 0; j < 4; j++) {
        float v = a[j]; __bf16 h = (__bf16)v;
        f.hi[j] = h; f.lo[j] = (__bf16)(v - (float)h);
    }
    #pragma unroll
    for (int j = 0; j < 4; j++) {
        float v = b[j]; __bf16 h = (__bf16)v;
        f.hi[4 + j] = h; f.lo[4 + j] = (__bf16)(v - (float)h);
    }
    return f;
}
__device__ __forceinline__ bf16x8 load_w(const float* p) {   // W: bf16 RNE hi only
    f32x4 a = *(const f32x4*)p, b = *(const f32x4*)(p + 4);
    bf16x8 w;
    #pragma unroll
    for (int j = 0; j < 4; j++) { w[j] = (__bf16)a[j]; w[4 + j] = (__bf16)b[j]; }
    return w;
}

// ---------- intra-block group sync (LDS, workgroup scope) ----------
__device__ __forceinline__ void wg_store(unsigned* p, unsigned k) {
    __hip_atomic_store(p, k, __ATOMIC_RELEASE, __HIP_MEMORY_SCOPE_WORKGROUP);
}
__device__ __forceinline__ unsigned wg_load_rlx(const unsigned* p) {
    return __hip_atomic_load(p, __ATOMIC_RELAXED, __HIP_MEMORY_SCOPE_WORKGROUP);
}
// 4-wave group barrier: per-wave monotone arrival slots (no reset, race-free).
__device__ __forceinline__ void group_barrier(unsigned* sl, int wg, int lane, unsigned k) {
    if (lane == 0) wg_store(&sl[wg], k);        // release: prior LDS writes visible
    for (;;) {
        unsigned a = wg_load_rlx(&sl[0]), b = wg_load_rlx(&sl[1]);
        unsigned c = wg_load_rlx(&sl[2]), d = wg_load_rlx(&sl[3]);
        if (a >= k && b >= k && c >= k && d >= k) break;
        __builtin_amdgcn_s_sleep(1);
    }
    __builtin_amdgcn_fence(__ATOMIC_ACQUIRE, "workgroup");
}
// cached monotone counter wait: zero LDS traffic when 'seen' already covers k
__device__ __forceinline__ unsigned wait_counter(unsigned* p, unsigned k, unsigned seen) {
    if (seen >= k) return seen;
    unsigned v;
    for (;;) {
        v = __hip_atomic_load(p, __ATOMIC_ACQUIRE, __HIP_MEMORY_SCOPE_WORKGROUP);
        if (v >= k) break;
        __builtin_amdgcn_s_sleep(1);
    }
    return v;
}

// Decoupled producer/consumer schedule (R13 math, zero s_barrier in loop):
//   waves 0-3 (G): GRU. ONE group-rendezvous per step.
//     step t: read h(t-1) frags [sHG[(t-1)&1]] + x(t) frags [sX[t&3]];
//       score(t-1) from the same h(t-1) frags -> sScore[(t-1)&3];
//       12 gate MFMA -> h(t) -> publish sHG[t&1]; stage x(t+1) -> sX[(t+1)&3];
//       gbar(t+1); wg0 releases prod=t+1.
//     throttle: before step t require cons >= t-2 (ring WAR, lead <= 3).
//   waves 4-7 (A): AUGRU, lags G by >=1 step. TWO group-rendezvous per step.
//     step t: wait prod >= t+1;
//       phase(i): finalize ha(t-1) (rh frags + score(t-1)), publish sHA;
//                 x(t) frags -> r/z/h x-part MFMAs;
//       abar(2t+1);
//       phase(ii): ha frags -> r/z h-part MFMAs, sigf, publish sRH;
//       abar(2t+2); wg0 releases cons=t+1.
// Hazard audit: every producer->consumer and WAR crosses a group barrier or is
// ordered by the prod/cons release/acquire chain (ring depth 4, lead band [1,3]):
//   sX slot s written at G-step s-1 (s=t+1), read by G-step s (1 gbar) and
//     A-step s (prod>=s+1 > s). Rewrite at G-step s+3 requires cons>=s+1 = A-step s done.
//   sScore slot (t-1)&3: W G-step t, R A-step t (prod>=t+1). Rewrite G-step t+4
//     requires cons>=t+2 = A-step t+1 done.
//   sHG[2]: W step t buf t&1, R step t+1 (1 gbar); WAR: R of buf at t+1 precedes
//     gbar(t+2) which precedes W at t+2.
//   sHA: W phase(i) t, R phase(ii) t (abar 2t+1); WAR: R at t-1 precedes abar(2t)
//     which precedes W at t. sRH: W phase(ii) t, R phase(i) t+1 (abar 2t+2); sym.
__global__ __launch_bounds__(512, 2)
void dien_fused(const int* __restrict__ u_idx, const int* __restrict__ i_idx,
                const int* __restrict__ seq, const float* __restrict__ item_emb,
                const float* __restrict__ user_bias, const float* __restrict__ item_bias,
                const float* __restrict__ gw_ih, const float* __restrict__ gb_ih,
                const float* __restrict__ gw_hh, const float* __restrict__ gb_hh,
                const float* __restrict__ attn_w, const float* __restrict__ attn_b,
                const float* __restrict__ wr_w, const float* __restrict__ wr_b,
                const float* __restrict__ wz_w, const float* __restrict__ wz_b,
                const float* __restrict__ wh_w, const float* __restrict__ wh_b,
                const float* __restrict__ aux_w, const float* __restrict__ aux_b,
                float* __restrict__ out)
{
    __shared__ int sSeq[16][T_LEN];
    __shared__ __align__(16) float sTP[16][64];
    __shared__ __align__(16) unsigned short sHG[2][16][72];
    __shared__ __align__(16) unsigned short sHA[16][72];
    __shared__ __align__(16) unsigned short sRH[16][72];
    __shared__ __align__(16) unsigned short sX[4][16][72];
    __shared__ float sScore[4][16];
    __shared__ float sParts[16][4];
    __shared__ __align__(16) unsigned gsl[4];
    __shared__ __align__(16) unsigned asl[4];
    __shared__ unsigned prodC, consC;

    const int tid  = threadIdx.x;
    const int wave = tid >> 6;           // 0..7
    const int lane = tid & 63;
    const int c    = lane & 15;
    const int q    = lane >> 4;
    const bool isG = (wave < 4);
    const int wg   = wave & 3;
    const int dglob = wg * 16 + c;
    const int row0 = blockIdx.x * 16;
    const int xrow = wg * 4 + q;         // G: staging row
    const int xch  = c;                  // G: 4-float chunk

    // ---- stage seq indices ----
    for (int i = tid; i < 16 * T_LEN; i += 512) {
        int b = i / T_LEN, t = i - b * T_LEN;
        sSeq[b][t] = seq[(row0 + b) * T_LEN + t];
    }

    // ---- fm1 ----
    if (tid < 16) {
        int b = row0 + tid;
        out[b] = user_bias[u_idx[b]] + item_bias[i_idx[b]];
    }

    // ---- target_proj (16x64 fp32), threads 0..255 ----
    if (tid < 256) {
        int b  = tid >> 4;
        int d0 = (tid & 15) * 4;
        const float* erow = item_emb + (long)i_idx[row0 + b] * 64;
        float e[64];
        #pragma unroll
        for (int k4 = 0; k4 < 16; k4++) {
            f32x4 v = *(const f32x4*)(erow + k4 * 4);
            #pragma unroll
            for (int j = 0; j < 4; j++) e[k4 * 4 + j] = v[j];
        }
        #pragma unroll
        for (int dd = 0; dd < 4; dd++) {
            int d = d0 + dd;
            const float* wrow = attn_w + d * 64;
            float s = attn_b[d];
            #pragma unroll
            for (int k4 = 0; k4 < 16; k4++) {
                f32x4 wv = *(const f32x4*)(wrow + k4 * 4);
                #pragma unroll
                for (int j = 0; j < 4; j++) s += e[k4 * 4 + j] * wv[j];
            }
            sTP[b][d] = s;
        }
    }

    // ---- zero sHA (A reads at t=0) and sHG[1] (G reads h(-1)=0); counters ----
    for (int i = tid; i < 16 * 72; i += 512) {
        ((unsigned short*)sHA)[i]    = 0;
        ((unsigned short*)sHG[1])[i] = 0;
    }
    if (tid < 4) { gsl[tid] = 0; asl[tid] = 0; }
    if (tid == 0) { prodC = 0; consC = 0; }
    // ---- prime sX[0] with x(0) ----
    if (isG) {
        const float* p = item_emb + (long)seq[(row0 + xrow) * T_LEN + 0] * 64 + xch * 4;
        f32x4 v = *(const f32x4*)p;
        *(uint2*)&sX[0][xrow][xch * 4] =
            make_uint2(packRNE2(v[0], v[1]), packRNE2(v[2], v[3]));
    }
    __syncthreads();   // only block-wide barrier; none inside the loops

    // ---- register-resident weights (bf16-hi RNE), unioned across groups ----
    // G: W[0..1]=wih_r, W[2..3]=wih_z, W[4..5]=wih_n, W[6..7]=whh_r, W[8..9]=whh_z, W[10..11]=whh_n
    // A: W[0..1]=wrx, W[2..3]=wrh, W[4..5]=wzx, W[6..7]=wzh, W[8..9]=whx, W[10..11]=whhat
    bf16x8 W[12];
    if (isG) {
        #pragma unroll
        for (int g = 0; g < 3; g++)
            #pragma unroll
            for (int s = 0; s < 2; s++) {
                W[g * 2 + s]     = load_w(gw_ih + (g * 64 + dglob) * 64 + s * 32 + q * 8);
                W[6 + g * 2 + s] = load_w(gw_hh + (g * 64 + dglob) * 64 + s * 32 + q * 8);
            }
    } else {
        #pragma unroll
        for (int s = 0; s < 2; s++) {
            const int fo = dglob * 128 + s * 32 + q * 8;
            W[0 + s]  = load_w(wr_w + fo);
            W[2 + s]  = load_w(wr_w + fo + 64);
            W[4 + s]  = load_w(wz_w + fo);
            W[6 + s]  = load_w(wz_w + fo + 64);
            W[8 + s]  = load_w(wh_w + fo);
            W[10 + s] = load_w(wh_w + fo + 64);
        }
    }

    float bA, bB, bC, bD;
    if (isG) {
        bA = gb_ih[dglob] + gb_hh[dglob];
        bB = gb_ih[64 + dglob] + gb_hh[64 + dglob];
        bC = gb_ih[128 + dglob];
        bD = gb_hh[128 + dglob];
    } else {
        bA = wr_b[dglob];
        bB = wz_b[dglob];
        bC = wh_b[dglob];
        bD = 0.0f;
    }

    if (isG) {
        // ================= GRU producer group =================
        const float auxwc = aux_w[dglob];
        Frag tpB0 = make_frag(*(const f32x4*)&sTP[c][q * 8], *(const f32x4*)&sTP[c][q * 8 + 4]);
        Frag tpB1 = make_frag(*(const f32x4*)&sTP[c][32 + q * 8], *(const f32x4*)&sTP[c][32 + q * 8 + 4]);

        float hst[4] = {0.f, 0.f, 0.f, 0.f};
        f32x4 xnxt = *(const f32x4*)(item_emb + (long)sSeq[xrow][1] * 64 + xch * 4);
        unsigned consSeen = 0;

        for (int t = 0; t < T_LEN; t++) {
            // ring-WAR throttle: lead over A capped at 3
            if (t >= 3) consSeen = wait_counter(&consC, (unsigned)(t - 2), consSeen);

            bf16x8 x0  = *(const bf16x8*)&sX[t & 3][c][q * 8];
            bf16x8 x1  = *(const bf16x8*)&sX[t & 3][c][32 + q * 8];
            bf16x8 fr0 = *(const bf16x8*)&sHG[(t + 1) & 1][c][q * 8];   // h(t-1)
            bf16x8 fr1 = *(const bf16x8*)&sHG[(t + 1) & 1][c][32 + q * 8];

            int tn = t + 2; if (tn > T_LEN - 1) tn = T_LEN - 1;
            f32x4 xg = *(const f32x4*)(item_emb + (long)sSeq[xrow][tn] * 64 + xch * 4);

            // score(t-1) from h(t-1) frags (already in regs)
            if (t > 0) {
                f32x4 sc = {0.f, 0.f, 0.f, 0.f};
                sc = mfma16(fr0, tpB0.hi, sc); sc = mfma16(fr0, tpB0.lo, sc);
                sc = mfma16(fr1, tpB1.hi, sc); sc = mfma16(fr1, tpB1.lo, sc);
                if (wg == 0 && (c >> 2) == q) {
                    int i = c & 3;
                    float d = (i == 0) ? sc[0] : (i == 1) ? sc[1] : (i == 2) ? sc[2] : sc[3];
                    sScore[(t - 1) & 3][c] = sigf(d);
                }
            }

            f32x4 accR = {bA, bA, bA, bA};
            accR = mfma16(x0, W[0], accR); accR = mfma16(x1, W[1], accR);
            accR = mfma16(fr0, W[6], accR); accR = mfma16(fr1, W[7], accR);
            f32x4 accZ = {bB, bB, bB, bB};
            accZ = mfma16(x0, W[2], accZ); accZ = mfma16(x1, W[3], accZ);
            accZ = mfma16(fr0, W[8], accZ); accZ = mfma16(fr1, W[9], accZ);
            f32x4 accNX = {bC, bC, bC, bC};
            accNX = mfma16(x0, W[4], accNX); accNX = mfma16(x1, W[5], accNX);
            f32x4 accNH = {bD, bD, bD, bD};
            accNH = mfma16(fr0, W[10], accNH); accNH = mfma16(fr1, W[11], accNH);

            #pragma unroll
            for (int i = 0; i < 4; i++) {
                float r = sigf(accR[i]);
                float z = sigf(accZ[i]);
                float n = tanh_fast(accNX[i] + r * accNH[i]);
                float hn = n + z * (hst[i] - n);
                hst[i] = hn;
                publish_hi(&sHG[t & 1][q * 4 + i][dglob], hn);
            }

            // stage x(t+1) from the register loaded one step ago
            *(uint2*)&sX[(t + 1) & 3][xrow][xch * 4] =
                make_uint2(packRNE2(xnxt[0], xnxt[1]), packRNE2(xnxt[2], xnxt[3]));
            xnxt = xg;

            group_barrier(gsl, wg, lane, (unsigned)(t + 1));
            if (wg == 0 && lane == 0) wg_store(&prodC, (unsigned)(t + 1));
        }

        // ---- G epilogue: score(T-1) (wg0 only), then release prod=T+1 ----
        if (wg == 0) {
            bf16x8 f0 = *(const bf16x8*)&sHG[(T_LEN - 1) & 1][c][q * 8];
            bf16x8 f1 = *(const bf16x8*)&sHG[(T_LEN - 1) & 1][c][32 + q * 8];
            f32x4 sc = {0.f, 0.f, 0.f, 0.f};
            sc = mfma16(f0, tpB0.hi, sc); sc = mfma16(f0, tpB0.lo, sc);
            sc = mfma16(f1, tpB1.hi, sc); sc = mfma16(f1, tpB1.lo, sc);
            if ((c >> 2) == q) {
                int i = c & 3;
                float d = (i == 0) ? sc[0] : (i == 1) ? sc[1] : (i == 2) ? sc[2] : sc[3];
                sScore[(T_LEN - 1) & 3][c] = sigf(d);
            }
            if (lane == 0) wg_store(&prodC, (unsigned)(T_LEN + 1));
        }

        // ---- aux_logits (G-group only) ----
        {
            float pa[4];
            #pragma unroll
            for (int i = 0; i < 4; i++) pa[i] = hst[i] * auxwc;
            #pragma unroll
            for (int m = 1; m < 16; m <<= 1) {
                #pragma unroll
                for (int i = 0; i < 4; i++) pa[i] += __shfl_xor(pa[i], m, 64);
            }
            if (c == 0) {
                #pragma unroll
                for (int i = 0; i < 4; i++) sParts[q * 4 + i][wg] = pa[i];
            }
        }
        group_barrier(gsl, wg, lane, (unsigned)(T_LEN + 1));
        if (tid < 16) {
            out[NB + NB * 64 + row0 + tid] =
                sParts[tid][0] + sParts[tid][1] + sParts[tid][2] + sParts[tid][3] + aux_b[0];
        }
    } else {
        // ================= AUGRU consumer group =================
        float hst[4] = {0.f, 0.f, 0.f, 0.f};
        f32x4 aAH = {0.f, 0.f, 0.f, 0.f};
        float z_c[4] = {0.f, 0.f, 0.f, 0.f};
        unsigned prodSeen = 0;

        for (int t = 0; t < T_LEN; t++) {
            prodSeen = wait_counter(&prodC, (unsigned)(t + 1), prodSeen);

            bf16x8 x0 = *(const bf16x8*)&sX[t & 3][c][q * 8];
            bf16x8 x1 = *(const bf16x8*)&sX[t & 3][c][32 + q * 8];

            // ---- phase (i): finalize ha(t-1), then x-part preactivations ----
            if (t > 0) {
                bf16x8 rh0 = *(const bf16x8*)&sRH[c][q * 8];
                bf16x8 rh1 = *(const bf16x8*)&sRH[c][32 + q * 8];
                aAH = mfma16(rh0, W[10], aAH); aAH = mfma16(rh1, W[11], aAH);
                #pragma unroll
                for (int i = 0; i < 4; i++) {
                    int rr = q * 4 + i;
                    float a = sScore[(t - 1) & 3][rr];   // pre-sigmoided
                    float hh = tanh_fast(aAH[i]);
                    float zz = a * z_c[i];
                    float hv = hst[i] + zz * (hh - hst[i]);
                    hst[i] = hv;
                    publish_hi(&sHA[rr][dglob], hv);
                }
            }
            f32x4 aAR = {bA, bA, bA, bA};
            aAR = mfma16(x0, W[0], aAR); aAR = mfma16(x1, W[1], aAR);
            f32x4 aAZ = {bB, bB, bB, bB};
            aAZ = mfma16(x0, W[4], aAZ); aAZ = mfma16(x1, W[5], aAZ);
            aAH = (f32x4){bC, bC, bC, bC};
            aAH = mfma16(x0, W[8], aAH); aAH = mfma16(x1, W[9], aAH);

            group_barrier(asl, wg, lane, (unsigned)(2 * t + 1));

            // ---- phase (ii): h-part of r/z, publish rh(t) ----
            bf16x8 ha0 = *(const bf16x8*)&sHA[c][q * 8];
            bf16x8 ha1 = *(const bf16x8*)&sHA[c][32 + q * 8];
            aAR = mfma16(ha0, W[2], aAR); aAR = mfma16(ha1, W[3], aAR);
            aAZ = mfma16(ha0, W[6], aAZ); aAZ = mfma16(ha1, W[7], aAZ);
            #pragma unroll
            for (int i = 0; i < 4; i++) {
                float r = sigf(aAR[i]);
                z_c[i]  = sigf(aAZ[i]);
                float rh = r * hst[i];
                publish_hi(&sRH[q * 4 + i][dglob], rh);
            }

            group_barrier(asl, wg, lane, (unsigned)(2 * t + 2));
            if (wg == 0 && lane == 0) wg_store(&consC, (unsigned)(t + 1));
        }

        // ---- A epilogue: finalize ha(T-1), write attn_vec ----
        prodSeen = wait_counter(&prodC, (unsigned)(T_LEN + 1), prodSeen);
        bf16x8 rh0 = *(const bf16x8*)&sRH[c][q * 8];
        bf16x8 rh1 = *(const bf16x8*)&sRH[c][32 + q * 8];
        aAH = mfma16(rh0, W[10], aAH); aAH = mfma16(rh1, W[11], aAH);
        #pragma unroll
        for (int i = 0; i < 4; i++) {
            int rr = q * 4 + i;
            float a = sScore[(T_LEN - 1) & 3][rr];
            float hh = tanh_fast(aAH[i]);
            float zz = a * z_c[i];
            float hv = hst[i] + zz * (hh - hst[i]);
            out[NB + (row0 + rr) * 64 + dglob] = hv;
        }
    }
}

extern "C" void kernel_launch(void* const* d_in, const int* in_sizes, int n_in,
                              void* d_out, int out_size, void* d_ws, size_t ws_size,
                              hipStream_t stream) {
    dien_fused<<<dim3(256), dim3(512), 0, stream>>>(
        (const int*)d_in[0],      // u_idx
        (const int*)d_in[1],      // i_idx
        (const int*)d_in[2],      // seq
        (const float*)d_in[3],    // item_emb
        (const float*)d_in[4],    // user_bias
        (const float*)d_in[5],    // item_bias
        (const float*)d_in[6],    // gru_w_ih
        (const float*)d_in[7],    // gru_b_ih
        (const float*)d_in[8],    // gru_w_hh
        (const float*)d_in[9],    // gru_b_hh
        (const float*)d_in[10],   // attn_w
        (const float*)d_in[11],   // attn_b
        (const float*)d_in[12],   // wr_w
        (const float*)d_in[13],   // wr_b
        (const float*)d_in[14],   // wz_w
        (const float*)d_in[15],   // wz_b
        (const float*)d_in[16],   // wh_w
        (const float*)d_in[17],   // wh_b
        (const float*)d_in[18],   // aux_w
        (const float*)d_in[19],   // aux_b
        (float*)d_out);
}

// Round 7
// 272.250 us; speedup vs baseline: 1.1825x; 1.1825x over previous
//
#include <hip/hip_runtime.h>

typedef __bf16 bf16x8 __attribute__((ext_vector_type(8)));
typedef float f32x4 __attribute__((ext_vector_type(4)));

#define T_LEN 200
#define NB 4096

__device__ __forceinline__ f32x4 mfma16(bf16x8 a, bf16x8 b, f32x4 c) {
    return __builtin_amdgcn_mfma_f32_16x16x32_bf16(a, b, c, 0, 0, 0);
}
// raw v_rcp_f32 (1 ulp) transcendentals; saturation exact (rcp(inf)=0)
__device__ __forceinline__ float sigf(float x) {
    return __builtin_amdgcn_rcpf(1.0f + __expf(-x));
}
__device__ __forceinline__ float tanh_fast(float x) {
    return 1.0f - 2.0f * __builtin_amdgcn_rcpf(__expf(2.0f * x) + 1.0f);
}
__device__ __forceinline__ unsigned packRNE2(float a, float b) {
    unsigned ha = (unsigned)__builtin_bit_cast(unsigned short, (__bf16)a);
    unsigned hb = (unsigned)__builtin_bit_cast(unsigned short, (__bf16)b);
    return ha | (hb << 16);
}
struct Frag { bf16x8 hi, lo; };
__device__ __forceinline__ Frag make_frag(f32x4 a, f32x4 b) {
    Frag f;
    #pragma unroll
    for (int j = 0; j < 4; j++) {
        float v = a[j]; __bf16 h = (__bf16)v;
        f.hi[j] = h; f.lo[j] = (__bf16)(v - (float)h);
    }
    #pragma unroll
    for (int j = 0; j < 4; j++) {
        float v = b[j]; __bf16 h = (__bf16)v;
        f.hi[4 + j] = h; f.lo[4 + j] = (__bf16)(v - (float)h);
    }
    return f;
}
__device__ __forceinline__ bf16x8 load_w(const float* p) {   // W: bf16 RNE hi only
    f32x4 a = *(const f32x4*)p, b = *(const f32x4*)(p + 4);
    bf16x8 w;
    #pragma unroll
    for (int j = 0; j < 4; j++) { w[j] = (__bf16)a[j]; w[4 + j] = (__bf16)b[j]; }
    return w;
}

// Schedule = R13 lockstep structure (186us measured; best of 7 variants).
// CHANGES THIS ROUND (arithmetic-identical, issue-work reduction only):
//  1. MFMA operand swap: gates computed as mfma(W, x/h, acc) instead of
//     mfma(x/h, W, acc). A-frag and B-frag lane layouts are identical for
//     16x16 operands, so all existing loads/frag reads are unchanged; only
//     the C/D thread mapping flips to [row=c][dims=wg*16+q*4+i]. Each
//     thread's 4 gate values are now CONTIGUOUS in dim -> every publish
//     (hg/ha/rh) is ONE ds_write_b64 instead of FOUR ds_write_u16, and the
//     attn epilogue is one global dwordx4. Biases become f32x4 loads.
//  2. Score MFMAs (hg.tp diag) only on wave wg0 (others' results were
//     discarded): -12 MFMA/step/block. Score path keeps the ORIGINAL
//     (unswapped) operand order -> extraction logic unchanged.
// 8 waves: 0-3 GRU (G), 4-7 AUGRU (A). AUGRU pipelined one step.
// LDS hazards (unchanged from R13):
//   sX  : W by G in S1(t) [x(t+1)], R by G+A in S0(t+1)   [b_end]
//   sHG : W by G in S0(t), R by G in S1(t)                 [b_mid]
//   sScore[p]: W by G(wg0) in S1(t) (p=t&1, pre-sigmoided), R by A in S0(t+1) [b_end]
//   sHA : W by A in S0(t), R by A in S1(t)                 [b_mid]
//   sRH : W by A in S1(t), R by A in S0(t+1)/epilogue      [b_end]
__global__ __launch_bounds__(512, 2)
void dien_fused(const int* __restrict__ u_idx, const int* __restrict__ i_idx,
                const int* __restrict__ seq, const float* __restrict__ item_emb,
                const float* __restrict__ user_bias, const float* __restrict__ item_bias,
                const float* __restrict__ gw_ih, const float* __restrict__ gb_ih,
                const float* __restrict__ gw_hh, const float* __restrict__ gb_hh,
                const float* __restrict__ attn_w, const float* __restrict__ attn_b,
                const float* __restrict__ wr_w, const float* __restrict__ wr_b,
                const float* __restrict__ wz_w, const float* __restrict__ wz_b,
                const float* __restrict__ wh_w, const float* __restrict__ wh_b,
                const float* __restrict__ aux_w, const float* __restrict__ aux_b,
                float* __restrict__ out)
{
    __shared__ int sSeq[16][T_LEN];
    __shared__ __align__(16) float sTP[16][64];
    __shared__ __align__(16) unsigned short sHGhi[16][72];
    __shared__ __align__(16) unsigned short sHAhi[16][72];
    __shared__ __align__(16) unsigned short sRHhi[16][72];
    __shared__ __align__(16) unsigned short sXhi[16][72];
    __shared__ float sScore[2][16];
    __shared__ float sParts[16][4];

    const int tid  = threadIdx.x;
    const int wave = tid >> 6;           // 0..7
    const int lane = tid & 63;
    const int c    = lane & 15;
    const int q    = lane >> 4;
    const bool isG = (wave < 4);
    const int wg   = wave & 3;
    const int dglob = wg * 16 + c;       // weight-row index for frag loads
    const int dbase = wg * 16 + q * 4;   // thread's 4 output dims (swapped C/D layout)
    const int row0 = blockIdx.x * 16;

    // ---- stage seq indices ----
    for (int i = tid; i < 16 * T_LEN; i += 512) {
        int b = i / T_LEN, t = i - b * T_LEN;
        sSeq[b][t] = seq[(row0 + b) * T_LEN + t];
    }

    // ---- fm1 ----
    if (tid < 16) {
        int b = row0 + tid;
        out[b] = user_bias[u_idx[b]] + item_bias[i_idx[b]];
    }

    // ---- target_proj (16x64 fp32), threads 0..255 ----
    if (tid < 256) {
        int b  = tid >> 4;
        int d0 = (tid & 15) * 4;
        const float* erow = item_emb + (long)i_idx[row0 + b] * 64;
        float e[64];
        #pragma unroll
        for (int k4 = 0; k4 < 16; k4++) {
            f32x4 v = *(const f32x4*)(erow + k4 * 4);
            #pragma unroll
            for (int j = 0; j < 4; j++) e[k4 * 4 + j] = v[j];
        }
        #pragma unroll
        for (int dd = 0; dd < 4; dd++) {
            int d = d0 + dd;
            const float* wrow = attn_w + d * 64;
            float s = attn_b[d];
            #pragma unroll
            for (int k4 = 0; k4 < 16; k4++) {
                f32x4 wv = *(const f32x4*)(wrow + k4 * 4);
                #pragma unroll
                for (int j = 0; j < 4; j++) s += e[k4 * 4 + j] * wv[j];
            }
            sTP[b][d] = s;
        }
    }

    // ---- zero ha exchange buffer (A S1(0) reads it); prime sX with x(0) ----
    for (int i = tid; i < 16 * 72; i += 512) sHAhi[0][i] = 0;
    const int xrow = wg * 4 + q;             // producer row (G)
    const int xch  = c;                      // 4-float chunk within row
    if (isG) {
        const float* p = item_emb + (long)seq[(row0 + xrow) * T_LEN + 0] * 64 + xch * 4;
        f32x4 v = *(const f32x4*)p;
        *(uint2*)&sXhi[xrow][xch * 4] =
            make_uint2(packRNE2(v[0], v[1]), packRNE2(v[2], v[3]));
    }
    __syncthreads();

    // ---- register-resident weights (bf16-hi RNE), unioned across groups ----
    // A-operand frags now; layout identical to old B-frags -> loads unchanged.
    // G: W[0..1]=wih_r, W[2..3]=wih_z, W[4..5]=wih_n, W[6..7]=whh_r, W[8..9]=whh_z, W[10..11]=whh_n
    // A: W[0..1]=wrx, W[2..3]=wrh, W[4..5]=wzx, W[6..7]=wzh, W[8..9]=whx, W[10..11]=whhat
    bf16x8 W[12];
    if (isG) {
        #pragma unroll
        for (int g = 0; g < 3; g++)
            #pragma unroll
            for (int s = 0; s < 2; s++) {
                W[g * 2 + s]     = load_w(gw_ih + (g * 64 + dglob) * 64 + s * 32 + q * 8);
                W[6 + g * 2 + s] = load_w(gw_hh + (g * 64 + dglob) * 64 + s * 32 + q * 8);
            }
    } else {
        #pragma unroll
        for (int s = 0; s < 2; s++) {
            const int fo = dglob * 128 + s * 32 + q * 8;
            W[0 + s]  = load_w(wr_w + fo);
            W[2 + s]  = load_w(wr_w + fo + 64);
            W[4 + s]  = load_w(wz_w + fo);
            W[6 + s]  = load_w(wz_w + fo + 64);
            W[8 + s]  = load_w(wh_w + fo);
            W[10 + s] = load_w(wh_w + fo + 64);
        }
    }

    // ---- biases: f32x4 per thread (dims dbase..dbase+3) ----
    f32x4 bA4, bB4, bC4, bD4;
    if (isG) {
        bA4 = *(const f32x4*)(gb_ih + dbase)       + *(const f32x4*)(gb_hh + dbase);
        bB4 = *(const f32x4*)(gb_ih + 64 + dbase)  + *(const f32x4*)(gb_hh + 64 + dbase);
        bC4 = *(const f32x4*)(gb_ih + 128 + dbase);
        bD4 = *(const f32x4*)(gb_hh + 128 + dbase);
    } else {
        bA4 = *(const f32x4*)(wr_b + dbase);
        bB4 = *(const f32x4*)(wz_b + dbase);
        bC4 = *(const f32x4*)(wh_b + dbase);
        bD4 = (f32x4){0.f, 0.f, 0.f, 0.f};
    }

    // TP as B-fragment (score path keeps OLD operand order; wg0 only uses it)
    Frag tpB0, tpB1;
    if (isG) {
        tpB0 = make_frag(*(const f32x4*)&sTP[c][q * 8], *(const f32x4*)&sTP[c][q * 8 + 4]);
        tpB1 = make_frag(*(const f32x4*)&sTP[c][32 + q * 8], *(const f32x4*)&sTP[c][32 + q * 8 + 4]);
    }

    // ---- state (swapped layout: row c, dims dbase+i) ----
    float hst[4] = {0.f, 0.f, 0.f, 0.f};   // G: hg(t); A: ha(t-1)
    bf16x8 fr0, fr1;                        // G: hg(t-1) hi-frags
    #pragma unroll
    for (int j = 0; j < 8; j++) { fr0[j] = (__bf16)0.f; fr1[j] = (__bf16)0.f; }
    f32x4 aAH = {0.f, 0.f, 0.f, 0.f};
    float z_c[4] = {0.f, 0.f, 0.f, 0.f};

    // ---- x prefetch pipeline prologue (G): xnxt = x(1) ----
    f32x4 xnxt = {0.f, 0.f, 0.f, 0.f};
    if (isG) xnxt = *(const f32x4*)(item_emb + (long)sSeq[xrow][1] * 64 + xch * 4);

    for (int t = 0; t < T_LEN; t++) {
        f32x4 xg;         // G: x(t+2) raw (global), becomes xnxt at end of S1
        f32x4 aAR, aAZ;   // A: r/z preactivations, live S0 -> S1

        // ================= Section 0 =================
        bf16x8 x0 = *(const bf16x8*)&sXhi[c][q * 8];
        bf16x8 x1 = *(const bf16x8*)&sXhi[c][32 + q * 8];

        if (isG) {
            int tn = t + 2; if (tn > T_LEN - 1) tn = T_LEN - 1;
            xg = *(const f32x4*)(item_emb + (long)sSeq[xrow][tn] * 64 + xch * 4);

            f32x4 accR = bA4;
            accR = mfma16(W[0], x0, accR); accR = mfma16(W[1], x1, accR);
            accR = mfma16(W[6], fr0, accR); accR = mfma16(W[7], fr1, accR);
            f32x4 accZ = bB4;
            accZ = mfma16(W[2], x0, accZ); accZ = mfma16(W[3], x1, accZ);
            accZ = mfma16(W[8], fr0, accZ); accZ = mfma16(W[9], fr1, accZ);
            f32x4 accNX = bC4;
            accNX = mfma16(W[4], x0, accNX); accNX = mfma16(W[5], x1, accNX);
            f32x4 accNH = bD4;
            accNH = mfma16(W[10], fr0, accNH); accNH = mfma16(W[11], fr1, accNH);

            float hn[4];
            #pragma unroll
            for (int i = 0; i < 4; i++) {
                float r = sigf(accR[i]);
                float z = sigf(accZ[i]);
                float n = tanh_fast(accNX[i] + r * accNH[i]);
                hn[i] = n + z * (hst[i] - n);
                hst[i] = hn[i];
            }
            *(uint2*)&sHGhi[c][dbase] =
                make_uint2(packRNE2(hn[0], hn[1]), packRNE2(hn[2], hn[3]));
        } else {
            if (t > 0) {
                bf16x8 rh0 = *(const bf16x8*)&sRHhi[c][q * 8];
                bf16x8 rh1 = *(const bf16x8*)&sRHhi[c][32 + q * 8];
                aAH = mfma16(W[10], rh0, aAH); aAH = mfma16(W[11], rh1, aAH);
                float a = sScore[(t - 1) & 1][c];   // pre-sigmoided, row c
                float hv[4];
                #pragma unroll
                for (int i = 0; i < 4; i++) {
                    float hh = tanh_fast(aAH[i]);
                    float zz = a * z_c[i];
                    hv[i] = hst[i] + zz * (hh - hst[i]);
                    hst[i] = hv[i];
                }
                *(uint2*)&sHAhi[c][dbase] =
                    make_uint2(packRNE2(hv[0], hv[1]), packRNE2(hv[2], hv[3]));
            }
            aAR = bA4;
            aAR = mfma16(W[0], x0, aAR); aAR = mfma16(W[1], x1, aAR);
            aAZ = bB4;
            aAZ = mfma16(W[4], x0, aAZ); aAZ = mfma16(W[5], x1, aAZ);
            aAH = bC4;
            aAH = mfma16(W[8], x0, aAH); aAH = mfma16(W[9], x1, aAH);
        }

        __syncthreads();  // b_mid

        // ================= Section 1 =================
        if (isG) {
            fr0 = *(const bf16x8*)&sHGhi[c][q * 8];
            fr1 = *(const bf16x8*)&sHGhi[c][32 + q * 8];
            if (wg == 0) {
                // score(t) = diag(hg(t) . tp^T), OLD operand order (unchanged math)
                f32x4 sc = {0.f, 0.f, 0.f, 0.f};
                sc = mfma16(fr0, tpB0.hi, sc); sc = mfma16(fr0, tpB0.lo, sc);
                sc = mfma16(fr1, tpB1.hi, sc); sc = mfma16(fr1, tpB1.lo, sc);
                if ((c >> 2) == q) {
                    int i = c & 3;
                    float d = (i == 0) ? sc[0] : (i == 1) ? sc[1] : (i == 2) ? sc[2] : sc[3];
                    sScore[t & 1][c] = sigf(d);
                }
            }
            // stage x(t+1) (RNE bf16) into sX from the register loaded at S0(t-1)
            *(uint2*)&sXhi[xrow][xch * 4] =
                make_uint2(packRNE2(xnxt[0], xnxt[1]), packRNE2(xnxt[2], xnxt[3]));
            xnxt = xg;
        } else {
            bf16x8 ha0 = *(const bf16x8*)&sHAhi[c][q * 8];
            bf16x8 ha1 = *(const bf16x8*)&sHAhi[c][32 + q * 8];
            aAR = mfma16(W[2], ha0, aAR); aAR = mfma16(W[3], ha1, aAR);
            aAZ = mfma16(W[6], ha0, aAZ); aAZ = mfma16(W[7], ha1, aAZ);
            float rh[4];
            #pragma unroll
            for (int i = 0; i < 4; i++) {
                float r = sigf(aAR[i]);
                z_c[i]  = sigf(aAZ[i]);
                rh[i]   = r * hst[i];
            }
            *(uint2*)&sRHhi[c][dbase] =
                make_uint2(packRNE2(rh[0], rh[1]), packRNE2(rh[2], rh[3]));
        }

        __syncthreads();  // b_end
    }

    // ---- epilogue: A finalizes ha(T-1), writes attn_vec (contiguous x4) ----
    if (!isG) {
        bf16x8 rh0 = *(const bf16x8*)&sRHhi[c][q * 8];
        bf16x8 rh1 = *(const bf16x8*)&sRHhi[c][32 + q * 8];
        aAH = mfma16(W[10], rh0, aAH); aAH = mfma16(W[11], rh1, aAH);
        float a = sScore[(T_LEN - 1) & 1][c];
        f32x4 hv;
        #pragma unroll
        for (int i = 0; i < 4; i++) {
            float hh = tanh_fast(aAH[i]);
            float zz = a * z_c[i];
            hv[i] = hst[i] + zz * (hh - hst[i]);
        }
        *(f32x4*)(out + NB + (long)(row0 + c) * 64 + dbase) = hv;
    }

    // ---- aux_logits from hg(T-1) (G group; row c, dims dbase+i) ----
    if (isG) {
        f32x4 auxw4 = *(const f32x4*)(aux_w + dbase);
        float pa = hst[0] * auxw4[0] + hst[1] * auxw4[1]
                 + hst[2] * auxw4[2] + hst[3] * auxw4[3];
        pa += __shfl_xor(pa, 16, 64);
        pa += __shfl_xor(pa, 32, 64);
        if (q == 0) sParts[c][wg] = pa;
    }
    __syncthreads();
    if (tid < 16) {
        out[NB + NB * 64 + row0 + tid] =
            sParts[tid][0] + sParts[tid][1] + sParts[tid][2] + sParts[tid][3] + aux_b[0];
    }
}

extern "C" void kernel_launch(void* const* d_in, const int* in_sizes, int n_in,
                              void* d_out, int out_size, void* d_ws, size_t ws_size,
                              hipStream_t stream) {
    dien_fused<<<dim3(256), dim3(512), 0, stream>>>(
        (const int*)d_in[0],      // u_idx
        (const int*)d_in[1],      // i_idx
        (const int*)d_in[2],      // seq
        (const float*)d_in[3],    // item_emb
        (const float*)d_in[4],    // user_bias
        (const float*)d_in[5],    // item_bias
        (const float*)d_in[6],    // gru_w_ih
        (const float*)d_in[7],    // gru_b_ih
        (const float*)d_in[8],    // gru_w_hh
        (const float*)d_in[9],    // gru_b_hh
        (const float*)d_in[10],   // attn_w
        (const float*)d_in[11],   // attn_b
        (const float*)d_in[12],   // wr_w
        (const float*)d_in[13],   // wr_b
        (const float*)d_in[14],   // wz_w
        (const float*)d_in[15],   // wz_b
        (const float*)d_in[16],   // wh_w
        (const float*)d_in[17],   // wh_b
        (const float*)d_in[18],   // aux_w
        (const float*)d_in[19],   // aux_b
        (float*)d_out);
}